// Round 1
// baseline (356.313 us; speedup 1.0000x reference)
//
#include <hip/hip_runtime.h>

#define NT 256

namespace {

constexpr int kL0 = 8192;
constexpr int kL1 = 4100;  // (8192+6)/2 + 1
constexpr int kL2 = 2054;  // (4100+6)/2 + 1
constexpr int kL3 = 1031;  // (2054+6)/2 + 1
constexpr int kRows = 16 * 128;  // 2048

// workspace per-row layout (floats); all bases 16B-aligned
constexpr int kWsD1 = 0;      // 4104 (4100 valid)
constexpr int kWsD2 = 4104;   // 2056 (2054 valid)
constexpr int kWsD3 = 6160;   // 1032 (1031 valid)
constexpr int kWsA3 = 7192;   // 1032 (1031 valid)
constexpr int kWsStride = 8224;  // floats per row (32,896 B, 16B-aligned)

__constant__ __device__ const float kLO[8] = {-0.0105974018f, 0.0328830117f, 0.0308413818f, -0.1870348117f,
                                              -0.0279837694f, 0.6308807679f, 0.7148465706f, 0.2303778133f};
__constant__ __device__ const float kHI[8] = {-0.2303778133f, 0.7148465706f, -0.6308807679f, -0.0279837694f,
                                              0.1870348117f, 0.0308413818f, -0.0328830117f, -0.0105974018f};

// ---- Analysis: out[i] = sum_k w[k] * xp[2i+k], xp = reflect-pad(7).
// Pair-processing: outputs (2u, 2u+1) read s[4u-7 .. 4u+2]; interior pairs
// load s[4u-8 .. 4u+3] as 3 aligned float4. alo/ahi may be LDS or global.
__device__ __forceinline__ void analysis2(const float* __restrict__ s, int L, int Lo,
                                          float* __restrict__ alo, float* __restrict__ ahi)
{
  const int npairs = Lo >> 1;
  const int uHi = (L - 3) >> 2;  // last interior pair: 4u+2 <= L-1
  for (int u = (int)threadIdx.x; u < npairs; u += NT) {
    if (u >= 2 && u <= uHi) {
      const float4* s4 = (const float4*)(s + 4 * u - 8);
      const float4 v0 = s4[0], v1 = s4[1], v2 = s4[2];
      const float w[10] = {v0.y, v0.z, v0.w, v1.x, v1.y, v1.z, v1.w, v2.x, v2.y, v2.z};
      float lo0 = 0.f, hi0 = 0.f, lo1 = 0.f, hi1 = 0.f;
#pragma unroll
      for (int k = 0; k < 8; ++k) {
        lo0 = fmaf(kLO[k], w[k], lo0);
        hi0 = fmaf(kHI[k], w[k], hi0);
        lo1 = fmaf(kLO[k], w[k + 2], lo1);
        hi1 = fmaf(kHI[k], w[k + 2], hi1);
      }
      ((float2*)alo)[u] = make_float2(lo0, lo1);
      ((float2*)ahi)[u] = make_float2(hi0, hi1);
    } else {
      // boundary: scalar reflect path for outputs 2u and 2u+1
#pragma unroll
      for (int j = 0; j < 2; ++j) {
        const int i = 2 * u + j;
        const int base = 2 * i - 7;
        float slo = 0.f, shi = 0.f;
#pragma unroll
        for (int k = 0; k < 8; ++k) {
          int m = base + k;
          m = (m < 0) ? -m : m;
          m = (m >= L) ? (2 * L - 2 - m) : m;
          const float v = s[m];
          slo = fmaf(kLO[k], v, slo);
          shi = fmaf(kHI[k], v, shi);
        }
        alo[i] = slo;
        ahi[i] = shi;
      }
    }
  }
  if ((Lo & 1) && threadIdx.x == 0) {  // odd tail (level 3: Lo=1031)
    const int i = Lo - 1;
    const int base = 2 * i - 7;
    float slo = 0.f, shi = 0.f;
#pragma unroll
    for (int k = 0; k < 8; ++k) {
      int m = base + k;
      m = (m < 0) ? -m : m;
      m = (m >= L) ? (2 * L - 2 - m) : m;
      const float v = s[m];
      slo = fmaf(kLO[k], v, slo);
      shi = fmaf(kHI[k], v, shi);
    }
    alo[i] = slo;
    ahi[i] = shi;
  }
}

// ---- Transposed conv (stride 2) + center-crop(7), 4-tap polyphase.
// even i: taps (w7,w5,w3,w1) over s[q..q+3], q=(i+1)>>1; odd i: (w6,w4,w2,w0).
// Quad-processing: outputs 4t..4t+3 read s[2t..2t+5] = 3 float2; store float4.
__device__ __forceinline__ void synthT4(const float* __restrict__ s, float* __restrict__ d, int T,
                                        float e0, float e1, float e2, float e3,
                                        float o0, float o1, float o2, float o3)
{
  const float2* __restrict__ s2 = (const float2*)s;
  const int nq = T >> 2;
  for (int t = (int)threadIdx.x; t < nq; t += NT) {
    const float2 p0 = s2[t];          // s[2t],   s[2t+1]
    const float2 p1 = s2[t + 1];      // s[2t+2], s[2t+3]
    const float2 p2 = s2[t + 2];      // s[2t+4], s[2t+5]
    float4 r;
    r.x = fmaf(e3, p1.y, fmaf(e2, p1.x, fmaf(e1, p0.y, e0 * p0.x)));
    r.y = fmaf(o3, p2.x, fmaf(o2, p1.y, fmaf(o1, p1.x, o0 * p0.y)));
    r.z = fmaf(e3, p2.x, fmaf(e2, p1.y, fmaf(e1, p1.x, e0 * p0.y)));
    r.w = fmaf(o3, p2.y, fmaf(o2, p2.x, fmaf(o1, p1.y, o0 * p1.x)));
    ((float4*)d)[t] = r;
  }
  // tail (T % 4 == 2 for T=2054)
  const int i0 = T & ~3;
  for (int i = i0 + (int)threadIdx.x; i < T; i += NT) {
    const int q = (i + 1) >> 1;
    const bool odd = (i & 1) != 0;
    const float c0 = odd ? o0 : e0;
    const float c1 = odd ? o1 : e1;
    const float c2 = odd ? o2 : e2;
    const float c3 = odd ? o3 : e3;
    float r = c0 * s[q];
    r = fmaf(c1, s[q + 1], r);
    r = fmaf(c2, s[q + 2], r);
    r = fmaf(c3, s[q + 3], r);
    d[i] = r;
  }
}

// REC_LO polyphase taps
#define RL_E -0.0105974018f, 0.0308413818f, -0.0279837694f, 0.7148465706f
#define RL_O 0.0328830117f, -0.1870348117f, 0.6308807679f, 0.2303778133f
// REC_HI polyphase taps
#define RH_E -0.2303778133f, -0.6308807679f, 0.1870348117f, -0.0328830117f
#define RH_O 0.7148465706f, -0.0279837694f, 0.0308413818f, -0.0105974018f

// coalesced global->LDS copy, n multiple of 4, both 16B-aligned
__device__ __forceinline__ void stage4(const float* __restrict__ g, float* __restrict__ l, int n)
{
  const float4* g4 = (const float4*)g;
  float4* l4 = (float4*)l;
  const int nq = n >> 2;
  for (int i = (int)threadIdx.x; i < nq; i += NT) l4[i] = g4[i];
}

// ---- Kernel A: 3-level analysis. One block per row.
// LDS: a1(4104) + a2(2056) = 6160 floats = 24,640 B -> 6 blocks/CU (24 waves).
// d1/d2/d3/a3 go straight to workspace from the analysis inner loop.
__global__ __launch_bounds__(NT, 4) void dwt_analysis(const float* __restrict__ x,
                                                      float* __restrict__ ws)
{
  __shared__ __align__(16) float pool[6160];
  const int row = blockIdx.x;
  const float* __restrict__ xr = x + (size_t)row * kL0;
  float* __restrict__ wr = ws + (size_t)row * kWsStride;

  float* a1 = pool;         // [0,4104)
  float* a2 = pool + 4104;  // [4104,6160)

  analysis2(xr, kL0, kL1, a1, wr + kWsD1);   // level 1: a1 -> LDS, d1 -> ws
  __syncthreads();
  analysis2(a1, kL1, kL2, a2, wr + kWsD2);   // level 2: a2 -> LDS, d2 -> ws
  __syncthreads();
  analysis2(a2, kL2, kL3, wr + kWsA3, wr + kWsD3);  // level 3: both -> ws
}

// ---- Kernel B: per-band reconstruction. One block per (row, band).
// band 3: d1 -RH-> out                  (1 synth pass)
// band 2: d2 -RH-> t -RL-> out          (2 passes)
// band 1: d3 -RH-> t1 -RL-> t2 -RL-> out (3 passes)
// band 0: a3 -RL-> t1 -RL-> t2 -RL-> out (3 passes)
// LDS: 6160 floats (24,640 B) -> 6 blocks/CU; 8192 blocks total.
__global__ __launch_bounds__(NT, 4) void dwt_synth(const float* __restrict__ ws,
                                                   float* __restrict__ out)
{
  __shared__ __align__(16) float pool[6160];
  const int bid = blockIdx.x;
  const int row = bid >> 2;
  const int band = bid & 3;
  const float* __restrict__ wr = ws + (size_t)row * kWsStride;
  float* __restrict__ outr = out + (size_t)band * (size_t)kRows * kL0 + (size_t)row * kL0;

  if (band == 3) {
    stage4(wr + kWsD1, pool, 4104);
    __syncthreads();
    synthT4(pool, outr, kL0, RH_E, RH_O);
  } else if (band == 2) {
    stage4(wr + kWsD2, pool + 4104, 2056);
    __syncthreads();
    synthT4(pool + 4104, pool, kL1, RH_E, RH_O);   // t = convT(d2, RH), len 4100
    __syncthreads();
    synthT4(pool, outr, kL0, RL_E, RL_O);
  } else {
    const float* src = wr + (band == 1 ? kWsD3 : kWsA3);
    stage4(src, pool, 1032);                        // src at [0,1032)
    __syncthreads();
    if (band == 1) {
      synthT4(pool, pool + 4104, kL2, RH_E, RH_O);  // t1 at [4104,6160)
    } else {
      synthT4(pool, pool + 4104, kL2, RL_E, RL_O);
    }
    __syncthreads();
    synthT4(pool + 4104, pool, kL1, RL_E, RL_O);    // t2 at [0,4104), src dead
    __syncthreads();
    synthT4(pool, outr, kL0, RL_E, RL_O);
  }
}

}  // namespace

extern "C" void kernel_launch(void* const* d_in, const int* in_sizes, int n_in,
                              void* d_out, int out_size, void* d_ws, size_t ws_size,
                              hipStream_t stream)
{
  const float* x = (const float*)d_in[0];
  float* out = (float*)d_out;
  float* ws = (float*)d_ws;  // needs kRows * kWsStride * 4 B = 67.4 MB
  dwt_analysis<<<dim3(kRows), dim3(NT), 0, stream>>>(x, ws);
  dwt_synth<<<dim3(kRows * 4), dim3(NT), 0, stream>>>(ws, out);
}

// Round 4
// 319.476 us; speedup vs baseline: 1.1153x; 1.1153x over previous
//
#include <hip/hip_runtime.h>

#define NT 512

namespace {

constexpr int kL0 = 8192;
constexpr int kL1 = 4100;  // (8192+6)/2 + 1
constexpr int kL2 = 2054;  // (4100+6)/2 + 1
constexpr int kL3 = 1031;  // (2054+6)/2 + 1
constexpr int kRows = 16 * 128;  // 2048

__constant__ __device__ const float kLO[8] = {-0.0105974018f, 0.0328830117f, 0.0308413818f, -0.1870348117f,
                                              -0.0279837694f, 0.6308807679f, 0.7148465706f, 0.2303778133f};
__constant__ __device__ const float kHI[8] = {-0.2303778133f, 0.7148465706f, -0.6308807679f, -0.0279837694f,
                                              0.1870348117f, 0.0308413818f, -0.0328830117f, -0.0105974018f};

constexpr float cRL[8] = {0.2303778133f, 0.7148465706f, 0.6308807679f, -0.0279837694f,
                          -0.1870348117f, 0.0308413818f, 0.0328830117f, -0.0105974018f};
constexpr float cRH[8] = {-0.0105974018f, -0.0328830117f, 0.0308413818f, 0.1870348117f,
                          -0.0279837694f, -0.6308807679f, 0.7148465706f, -0.2303778133f};

// One synthesis stage (stride-2 convT + crop 7): out[i] = sum_j s[j] * w[i+7-2j],
// j in [ceil(i/2), ceil(i/2)+3]; never clamped for any valid i at any level
// (checked: outer i=8191 -> j<=4099; j=4099 -> m<=2053; m=2053 -> n<=1030).
// Composition is shift-invariant (i+4 -> m+1 for 2 stages; i+8 -> n+1 for 3),
// so a period-4 table over 6 taps (base (i+3)>>2) and a period-8 table over
// 7 taps (base (i+7)>>3) are exact everywhere. Computed at compile time in
// double precision; used as function-local constexpr so all coefficients fold
// to immediate operands (no device globals, no memory reads).
struct Tab2 { float c[4][6]; };
struct Tab3 { float c[8][7]; };

constexpr Tab2 compose2(const float (&w1)[8], const float (&w0)[8]) {
  double acc[4][6] = {};
  for (int r = 0; r < 4; ++r) {
    const int i = 16 + r;            // interior representative with residue r
    const int m0 = (i + 3) >> 2;
    for (int j = (i + 1) / 2; j <= (i + 7) / 2; ++j) {
      const double a = (double)w1[i + 7 - 2 * j];
      for (int m = (j + 1) / 2; m <= (j + 7) / 2; ++m)
        acc[r][m - m0] += a * (double)w0[j + 7 - 2 * m];
    }
  }
  Tab2 T{};
  for (int r = 0; r < 4; ++r)
    for (int t = 0; t < 6; ++t) T.c[r][t] = (float)acc[r][t];
  return T;
}

constexpr Tab3 compose3(const float (&w2)[8], const float (&w1)[8], const float (&w0)[8]) {
  double acc[8][7] = {};
  for (int r = 0; r < 8; ++r) {
    const int i = 64 + r;
    const int n0 = (i + 7) >> 3;
    for (int j = (i + 1) / 2; j <= (i + 7) / 2; ++j) {
      const double a = (double)w2[i + 7 - 2 * j];
      for (int m = (j + 1) / 2; m <= (j + 7) / 2; ++m) {
        const double b = a * (double)w1[j + 7 - 2 * m];
        for (int n = (m + 1) / 2; n <= (m + 7) / 2; ++n)
          acc[r][n - n0] += b * (double)w0[m + 7 - 2 * n];
      }
    }
  }
  Tab3 T{};
  for (int r = 0; r < 8; ++r)
    for (int t = 0; t < 7; ++t) T.c[r][t] = (float)acc[r][t];
  return T;
}

// ---- Analysis: out[i] = sum_k w[k] * xp[2i+k], xp = reflect-pad(7).
__device__ __forceinline__ void analysis2(const float* __restrict__ s, int L, int Lo,
                                          float* __restrict__ alo, float* __restrict__ ahi)
{
  const int npairs = Lo >> 1;
  const int uHi = (L - 3) >> 2;  // last interior pair: 4u+3 <= L-1
  for (int u = (int)threadIdx.x; u < npairs; u += NT) {
    if (u >= 2 && u <= uHi) {
      const float4* s4 = (const float4*)(s + 4 * u - 8);
      const float4 v0 = s4[0], v1 = s4[1], v2 = s4[2];
      const float w[10] = {v0.y, v0.z, v0.w, v1.x, v1.y, v1.z, v1.w, v2.x, v2.y, v2.z};
      float lo0 = 0.f, hi0 = 0.f, lo1 = 0.f, hi1 = 0.f;
#pragma unroll
      for (int k = 0; k < 8; ++k) {
        lo0 = fmaf(kLO[k], w[k], lo0);
        hi0 = fmaf(kHI[k], w[k], hi0);
        lo1 = fmaf(kLO[k], w[k + 2], lo1);
        hi1 = fmaf(kHI[k], w[k + 2], hi1);
      }
      ((float2*)alo)[u] = make_float2(lo0, lo1);
      ((float2*)ahi)[u] = make_float2(hi0, hi1);
    } else {
#pragma unroll
      for (int j = 0; j < 2; ++j) {
        const int i = 2 * u + j;
        const int base = 2 * i - 7;
        float slo = 0.f, shi = 0.f;
#pragma unroll
        for (int k = 0; k < 8; ++k) {
          int m = base + k;
          m = (m < 0) ? -m : m;
          m = (m >= L) ? (2 * L - 2 - m) : m;
          const float v = s[m];
          slo = fmaf(kLO[k], v, slo);
          shi = fmaf(kHI[k], v, shi);
        }
        alo[i] = slo;
        ahi[i] = shi;
      }
    }
  }
  if ((Lo & 1) && threadIdx.x == 0) {  // odd tail (level 3: Lo=1031)
    const int i = Lo - 1;
    const int base = 2 * i - 7;
    float slo = 0.f, shi = 0.f;
#pragma unroll
    for (int k = 0; k < 8; ++k) {
      int m = base + k;
      m = (m < 0) ? -m : m;
      m = (m >= L) ? (2 * L - 2 - m) : m;
      const float v = s[m];
      slo = fmaf(kLO[k], v, slo);
      shi = fmaf(kHI[k], v, shi);
    }
    alo[i] = slo;
    ahi[i] = shi;
  }
}

// ---- Single-stage transposed conv (band 3), T = 8192 (no tail).
__device__ __forceinline__ void synthT4(const float* __restrict__ s, float* __restrict__ d, int T,
                                        float e0, float e1, float e2, float e3,
                                        float o0, float o1, float o2, float o3)
{
  const float2* __restrict__ s2 = (const float2*)s;
  const int nq = T >> 2;
  for (int t = (int)threadIdx.x; t < nq; t += NT) {
    const float2 p0 = s2[t];
    const float2 p1 = s2[t + 1];
    const float2 p2 = s2[t + 2];
    float4 r;
    r.x = fmaf(e3, p1.y, fmaf(e2, p1.x, fmaf(e1, p0.y, e0 * p0.x)));
    r.y = fmaf(o3, p2.x, fmaf(o2, p1.y, fmaf(o1, p1.x, o0 * p0.y)));
    r.z = fmaf(e3, p2.x, fmaf(e2, p1.y, fmaf(e1, p1.x, e0 * p0.y)));
    r.w = fmaf(o3, p2.y, fmaf(o2, p2.x, fmaf(o1, p1.y, o0 * p1.x)));
    ((float4*)d)[t] = r;
  }
}

#define RH_E -0.2303778133f, -0.6308807679f, 0.1870348117f, -0.0328830117f
#define RH_O 0.7148465706f, -0.0279837694f, 0.0308413818f, -0.0105974018f

// ---- Composed 2-stage synthesis: d2 (len 2054) -> out (8192) in one pass.
// outputs 4v..4v+3 read s[v..v+6]; residue 0 taps at s[v..v+5], 1..3 at s[v+1..v+6].
__device__ __forceinline__ void synthC2(const float* __restrict__ s, float* __restrict__ d)
{
  constexpr Tab2 W = compose2(cRL, cRH);  // band2: RL(outer) o RH(inner)
  for (int v = (int)threadIdx.x; v < (kL0 >> 2); v += NT) {
    float w[7];
#pragma unroll
    for (int t = 0; t < 7; ++t) w[t] = s[v + t];
    float r[4];
#pragma unroll
    for (int p = 0; p < 4; ++p) {
      const int off = (p == 0) ? 0 : 1;
      float acc = W.c[p][0] * w[off];
#pragma unroll
      for (int t = 1; t < 6; ++t) acc = fmaf(W.c[p][t], w[off + t], acc);
      r[p] = acc;
    }
    ((float4*)d)[v] = make_float4(r[0], r[1], r[2], r[3]);
  }
}

// ---- Composed 3-stage synthesis: a3/d3 (len 1031) -> out (8192) in one pass.
// outputs 8v..8v+7 read s[v..v+7]; residue 0 taps at s[v..v+6], 1..7 at s[v+1..v+7].
// max read: v=1023 -> s[1030] (in range). HI: RL o RL o RH (band 1); else RL^3 (band 0).
template <bool HI>
__device__ __forceinline__ void synthC3(const float* __restrict__ s, float* __restrict__ d)
{
  constexpr Tab3 W = HI ? compose3(cRL, cRL, cRH) : compose3(cRL, cRL, cRL);
  for (int v = (int)threadIdx.x; v < (kL0 >> 3); v += NT) {
    float w[8];
#pragma unroll
    for (int t = 0; t < 8; ++t) w[t] = s[v + t];
    float r[8];
#pragma unroll
    for (int p = 0; p < 8; ++p) {
      const int off = (p == 0) ? 0 : 1;
      float acc = W.c[p][0] * w[off];
#pragma unroll
      for (int t = 1; t < 7; ++t) acc = fmaf(W.c[p][t], w[off + t], acc);
      r[p] = acc;
    }
    float4* d4 = (float4*)d;
    d4[2 * v] = make_float4(r[0], r[1], r[2], r[3]);
    d4[2 * v + 1] = make_float4(r[4], r[5], r[6], r[7]);
  }
}

// ---- Fused 4-phase kernel. One block (512 threads) per row.
// LDS peak (phase 2): a1+d1+a2+d2 = 12320 floats = 49,280 B -> 3 blocks/CU,
// 24 waves/CU. 3 barriers total (was 11 in the 12-phase version).
__global__ __launch_bounds__(NT, 6) void dwt_fused(const float* __restrict__ x,
                                                   float* __restrict__ out)
{
  __shared__ __align__(16) float pool[12320];
  const int row = blockIdx.x;
  const float* __restrict__ xr = x + (size_t)row * kL0;
  float* __restrict__ outr = out + (size_t)row * kL0;
  const size_t bs = (size_t)kRows * kL0;  // band stride

  float* a1 = pool;          // [0,4104)      P1-P2
  float* d1 = pool + 4104;   // [4104,8208)   P1-P2
  float* a2 = pool + 8208;   // [8208,10264)  P2-P3
  float* d2 = pool + 10264;  // [10264,12320) P2-P3
  float* a3 = pool;          // [0,1032)      P3-P4 (a1 dead)
  float* d3 = pool + 1032;   // [1032,2064)   P3-P4

  // P1: level-1 analysis from global
  analysis2(xr, kL0, kL1, a1, d1);
  __syncthreads();
  // P2: level-2 analysis  ||  band 3 = convT(d1, RH) -> global
  analysis2(a1, kL1, kL2, a2, d2);
  synthT4(d1, outr + 3 * bs, kL0, RH_E, RH_O);
  __syncthreads();
  // P3: level-3 analysis  ||  band 2 = composed RLoRH from d2 -> global
  analysis2(a2, kL2, kL3, a3, d3);
  synthC2(d2, outr + 2 * bs);
  __syncthreads();
  // P4: band 1 = composed RLoRLoRH from d3; band 0 = composed RL^3 from a3
  synthC3<true>(d3, outr + 1 * bs);
  synthC3<false>(a3, outr + 0 * bs);
}

}  // namespace

extern "C" void kernel_launch(void* const* d_in, const int* in_sizes, int n_in,
                              void* d_out, int out_size, void* d_ws, size_t ws_size,
                              hipStream_t stream)
{
  const float* x = (const float*)d_in[0];
  float* out = (float*)d_out;
  dwt_fused<<<dim3(kRows), dim3(NT), 0, stream>>>(x, out);
}